// Round 12
// baseline (481.383 us; speedup 1.0000x reference)
//
#include <hip/hip_runtime.h>
#include <hip/hip_bf16.h>

// ---------------------------------------------------------------------------
// PAWSA fused windowed attention, MI355X / gfx950 — round 12: 8-wave blocks.
// Inputs f32, output f32 (out0 [8192,49,96], out1 v_hw [8,3,96] at elem
// offset 38,535,168). One block per window, 512 threads (8 waves).
// LDS 51,696 B -> 3 blocks/CU = 24 waves/CU (6/SIMD), vs R11's 16 waves/CU.
//   - P is per-wave scratch [8][16][68] -> attention stays barrier-free.
//   - qt = wid&3 for ALL waves; waves 0-3 do heads {0,2}, waves 4-7 head {1}
//     (disjoint O col ranges; shared mask/bidx registers per wave).
//   - QKV tiles split {2,2,2,2,3,3,2,2} to offset attention imbalance.
//   - qkv_w/proj_w pre-converted to bf16 in d_ws by a prep kernel ->
//     weight fragments are single 16B loads (no f32->bf16 cvt chains).
//   - 2 barriers per window (post-scatter, pre-projection).
// Overread map (all finite or masked): XQ rows>48 -> K; K rows 52-63 -> P_w
// (garbage, feeds only logit cols >=52 masked to -1e30 pre-exp); proj A
// rows>48 -> K. VGPR capped 84 via __launch_bounds__(512,6); spill tripwire
// = FETCH/WRITE balloon.
// ---------------------------------------------------------------------------

typedef __bf16 bf16x8 __attribute__((ext_vector_type(8)));
typedef float  f32x4  __attribute__((ext_vector_type(4)));
typedef short  s16x4  __attribute__((ext_vector_type(4)));
using bf16 = __hip_bfloat16;

#define SCALE 0.17677669529663687f   // 32^-0.5

// LDS partition (units: 16-bit elements) — 25,848 shorts = 51,696 B
#define LDS_XQ    0       // [49][100] q (rows<49) -> O
#define LDS_K     4900    // [52][100] k
#define LDS_PW    10100   // [8][16][68] per-wave P scratch
#define LDS_VT    18804   // [96][68]  v transposed: vt[h*32+d][token]
#define LDS_BIAS  25332   // [516]     bias_table (bf16)
#define LDS_TOT   25848

static __device__ inline float s2f(short s) {
    unsigned int u = ((unsigned int)(unsigned short)s) << 16;
    float f;
    __builtin_memcpy(&f, &u, 4);
    return f;
}
static __device__ inline short f2s(float f) {
    bf16 h = __float2bfloat16(f);
    short s;
    __builtin_memcpy(&s, &h, 2);
    return s;
}
static __device__ inline bf16x8 ldw8(const float* p) {   // f32 -> bf16 fragment
    f32x4 a = *reinterpret_cast<const f32x4*>(p);
    f32x4 b = *reinterpret_cast<const f32x4*>(p + 4);
    bf16x8 r;
    #pragma unroll
    for (int i = 0; i < 4; ++i) {
        r[i]     = (__bf16)a[i];
        r[i + 4] = (__bf16)b[i];
    }
    return r;
}

// ---- prep: convert qkv_w (27648) + proj_w (9216) to bf16 in d_ws ----
__global__ __launch_bounds__(256)
void pawsa_prep(const float* __restrict__ qkv_w, const float* __restrict__ proj_w,
                bf16* __restrict__ ws)
{
    int i = blockIdx.x * 256 + threadIdx.x;
    if (i < 27648)      ws[i] = __float2bfloat16(qkv_w[i]);
    else if (i < 36864) ws[i] = __float2bfloat16(proj_w[i - 27648]);
}

__global__ __launch_bounds__(512, 6)
void pawsa_main(const float* __restrict__ x, const float* __restrict__ mask,
                const float* __restrict__ uk, const float* __restrict__ fg,
                const float* __restrict__ bg,
                const bf16* __restrict__ wq,    // bf16 qkv_w in d_ws
                const float* __restrict__ qkv_b,
                const bf16* __restrict__ wp,    // bf16 proj_w in d_ws
                const float* __restrict__ proj_b,
                const float* __restrict__ bias_table, float* __restrict__ out)
{
    __shared__ short smem[LDS_TOT];

    const int tid  = threadIdx.x;
    const int w    = blockIdx.x;       // window id
    const int b    = w >> 10;          // batch (nW = 1024)
    const int wi   = w & 1023;         // window-in-batch
    const int lane = tid & 63;
    const int wid  = tid >> 6;         // wave id 0..7
    const int lr   = lane & 15;        // row/col within 16-tile
    const int lg   = lane >> 4;        // k-group 0..3
    const int qt   = wid & 3;          // query row-tile owned by this wave

    // ---- X tile -> registers directly (rows<49 x, 49-51 priors, >=52 zero) --
    bf16x8 af[3][4];
    #pragma unroll
    for (int mt = 0; mt < 4; ++mt) {
        int n = mt * 16 + lr;
        #pragma unroll
        for (int ks = 0; ks < 3; ++ks) {
            bf16x8 a = (bf16x8)0;
            if (n < 49) {
                a = ldw8(x + ((size_t)w * 49 + n) * 96 + ks * 32 + lg * 8);
            } else if (n < 52) {
                const float* pr = (n == 49) ? uk : (n == 50) ? fg : bg;
                a = ldw8(pr + b * 96 + ks * 32 + lg * 8);
            }
            af[ks][mt] = a;
        }
    }

    // ---- QKV GEMM: tiles {2,2,2,2,3,3,2,2}, bf16 weights, immediate scatter --
    const int tcount = (wid == 4 || wid == 5) ? 3 : 2;
    const int tbase  = (wid < 4) ? 2 * wid
                     : (wid == 4) ? 8 : (wid == 5) ? 11 : 14 + 2 * (wid - 6);
    #pragma unroll
    for (int i = 0; i < 3; ++i) {
        if (i >= tcount) break;
        int o = (tbase + i) * 16 + lr;        // output channel 0..287
        bf16x8 bw0 = *reinterpret_cast<const bf16x8*>(wq + o * 96 +  0 + lg * 8);
        bf16x8 bw1 = *reinterpret_cast<const bf16x8*>(wq + o * 96 + 32 + lg * 8);
        bf16x8 bw2 = *reinterpret_cast<const bf16x8*>(wq + o * 96 + 64 + lg * 8);
        float  qb  = qkv_b[o];
        f32x4 acc[4] = {(f32x4)0.f, (f32x4)0.f, (f32x4)0.f, (f32x4)0.f};
        #pragma unroll
        for (int mt = 0; mt < 4; ++mt) {
            acc[mt] = __builtin_amdgcn_mfma_f32_16x16x32_bf16(af[0][mt], bw0, acc[mt], 0, 0, 0);
            acc[mt] = __builtin_amdgcn_mfma_f32_16x16x32_bf16(af[1][mt], bw1, acc[mt], 0, 0, 0);
            acc[mt] = __builtin_amdgcn_mfma_f32_16x16x32_bf16(af[2][mt], bw2, acc[mt], 0, 0, 0);
        }
        int s = o / 96;                       // 0=q 1=k 2=v
        int rem = o - s * 96;
        #pragma unroll
        for (int mt = 0; mt < 4; ++mt) {
            if (s == 2) {                     // v: 4 consecutive tokens -> b64
                s16x4 pk;
                #pragma unroll
                for (int j = 0; j < 4; ++j) pk[j] = f2s(acc[mt][j] + qb);
                *reinterpret_cast<s16x4*>(
                    &smem[LDS_VT + rem * 68 + mt * 16 + lg * 4]) = pk;
            } else {
                #pragma unroll
                for (int j = 0; j < 4; ++j) {
                    int n = mt * 16 + lg * 4 + j;
                    short hv = f2s(acc[mt][j] + qb);
                    if (s == 0) { if (n < 49) smem[LDS_XQ + n * 100 + rem] = hv; }
                    else        { if (n < 52) smem[LDS_K  + n * 100 + rem] = hv; }
                }
            }
        }
    }

    // ---- mask loads (af now dead; issued before barrier, consumed in heads) --
    float mk[4][4];
    #pragma unroll
    for (int nt = 0; nt < 4; ++nt) {
        int c = nt * 16 + lr;
        #pragma unroll
        for (int j = 0; j < 4; ++j) {
            int n = qt * 16 + lg * 4 + j;
            float m = 0.f;
            if (c < 49 && n < 49)
                m = mask[(size_t)wi * 2401 + n * 49 + c];
            mk[nt][j] = m;
        }
    }

    // ---- bias_table -> LDS ----
    for (int i = tid; i < 516; i += 512) smem[LDS_BIAS + i] = f2s(bias_table[i]);

    // REL_IDX packed (4 x u8 per int)
    int bidxp[4];
    #pragma unroll
    for (int nt = 0; nt < 4; ++nt) {
        int c = nt * 16 + lr;
        int p = 0;
        #pragma unroll
        for (int j = 0; j < 4; ++j) {
            int n = qt * 16 + lg * 4 + j;
            int idx = 171;
            if (c < 49) {
                idx = (n / 7 - c / 7 + 6) * 13 + ((n % 7) - (c % 7) + 6);
                if (idx > 171) idx = 171;     // garbage rows n>=49 (discarded)
            } else if (c < 52) {
                idx = 169 + (c - 49);
            }
            p |= idx << (8 * j);
        }
        bidxp[nt] = p;
    }

    __syncthreads();
    // From here: K, VT read-only; XQ rows x head-cols and P_w wave-private.

    // ---- attention: waves 0-3 do heads {0,2}; waves 4-7 do head {1} ----
    const int pbase = LDS_PW + wid * 1088;    // 16 rows x 68
    const int nheads = (wid < 4) ? 2 : 1;
    #pragma unroll
    for (int ui = 0; ui < 2; ++ui) {
        if (ui >= nheads) break;
        const int h = (wid < 4) ? (ui == 0 ? 0 : 2) : 1;

        bf16x8 aq = *reinterpret_cast<const bf16x8*>(
            &smem[LDS_XQ + (qt * 16 + lr) * 100 + h * 32 + lg * 8]);
        f32x4 sacc[4];
        #pragma unroll
        for (int nt = 0; nt < 4; ++nt) {
            bf16x8 bk = *reinterpret_cast<const bf16x8*>(
                &smem[LDS_K + (nt * 16 + lr) * 100 + h * 32 + lg * 8]);
            sacc[nt] = __builtin_amdgcn_mfma_f32_16x16x32_bf16(aq, bk, (f32x4)0.f, 0, 0, 0);
        }
        float lgt[4][4];
        #pragma unroll
        for (int nt = 0; nt < 4; ++nt) {
            int c = nt * 16 + lr;
            #pragma unroll
            for (int j = 0; j < 4; ++j) {
                float v = -1e30f;
                if (c < 52) {
                    int idx = (bidxp[nt] >> (8 * j)) & 255;
                    v = sacc[nt][j] * SCALE
                        + s2f(smem[LDS_BIAS + idx * 3 + h]) + mk[nt][j];
                }
                lgt[nt][j] = v;
            }
        }
        float pr[4][4];
        #pragma unroll
        for (int j = 0; j < 4; ++j) {
            float m = fmaxf(fmaxf(lgt[0][j], lgt[1][j]), fmaxf(lgt[2][j], lgt[3][j]));
            m = fmaxf(m, __shfl_xor(m, 1));
            m = fmaxf(m, __shfl_xor(m, 2));
            m = fmaxf(m, __shfl_xor(m, 4));
            m = fmaxf(m, __shfl_xor(m, 8));
            float sum = 0.f;
            #pragma unroll
            for (int nt = 0; nt < 4; ++nt) {
                pr[nt][j] = __expf(lgt[nt][j] - m);
                sum += pr[nt][j];
            }
            sum += __shfl_xor(sum, 1);
            sum += __shfl_xor(sum, 2);
            sum += __shfl_xor(sum, 4);
            sum += __shfl_xor(sum, 8);
            float inv = 1.0f / sum;
            #pragma unroll
            for (int nt = 0; nt < 4; ++nt) pr[nt][j] *= inv;
        }
        // P -> per-wave scratch (all 16 rows; garbage rows feed discarded O)
        #pragma unroll
        for (int nt = 0; nt < 4; ++nt)
            #pragma unroll
            for (int j = 0; j < 4; ++j)
                smem[pbase + (lg * 4 + j) * 68 + nt * 16 + lr] = f2s(pr[nt][j]);

        // O_h = P @ V (K=52 padded to 64; P cols 52-63 exact zeros)
        f32x4 ov[2] = {(f32x4)0.f, (f32x4)0.f};
        #pragma unroll
        for (int ks = 0; ks < 2; ++ks) {
            bf16x8 ap = *reinterpret_cast<const bf16x8*>(
                &smem[pbase + lr * 68 + ks * 32 + lg * 8]);
            #pragma unroll
            for (int nt2 = 0; nt2 < 2; ++nt2) {
                bf16x8 bv = *reinterpret_cast<const bf16x8*>(
                    &smem[LDS_VT + (h * 32 + nt2 * 16 + lr) * 68 + ks * 32 + lg * 8]);
                ov[nt2] = __builtin_amdgcn_mfma_f32_16x16x32_bf16(ap, bv, ov[nt2], 0, 0, 0);
            }
        }
        #pragma unroll
        for (int nt2 = 0; nt2 < 2; ++nt2)
            #pragma unroll
            for (int j = 0; j < 4; ++j) {
                int orow = qt * 16 + lg * 4 + j;
                if (orow < 49)
                    smem[LDS_XQ + orow * 100 + h * 32 + nt2 * 16 + lr]
                        = f2s(ov[nt2][j]);
            }
    }

    __syncthreads();   // all O columns complete before projection

    // ---- projection: wave = (row-tile rt, col-half ch): 16 rows x 48 cols ----
    const int rt = wid & 3, ch = wid >> 2;
    f32x4 po[3] = {(f32x4)0.f, (f32x4)0.f, (f32x4)0.f};
    #pragma unroll
    for (int ks = 0; ks < 3; ++ks) {
        bf16x8 a = *reinterpret_cast<const bf16x8*>(
            &smem[LDS_XQ + (rt * 16 + lr) * 100 + ks * 32 + lg * 8]);
        #pragma unroll
        for (int i = 0; i < 3; ++i) {
            int nt = ch * 3 + i;
            bf16x8 bp = *reinterpret_cast<const bf16x8*>(
                wp + (nt * 16 + lr) * 96 + ks * 32 + lg * 8);
            po[i] = __builtin_amdgcn_mfma_f32_16x16x32_bf16(a, bp, po[i], 0, 0, 0);
        }
    }
    #pragma unroll
    for (int i = 0; i < 3; ++i) {
        int col = (ch * 3 + i) * 16 + lr;
        float pb = proj_b[col];
        #pragma unroll
        for (int j = 0; j < 4; ++j) {
            int n = rt * 16 + lg * 4 + j;
            if (n < 49)
                out[((size_t)w * 49 + n) * 96 + col] = po[i][j] + pb;
        }
    }
}

// ---------------- prior highway: v_hw = proj(v(qkv(prior))) ----------------
__global__ __launch_bounds__(128)
void pawsa_prior(const float* __restrict__ uk, const float* __restrict__ fg,
                 const float* __restrict__ bg,
                 const float* __restrict__ qkv_w, const float* __restrict__ qkv_b,
                 const float* __restrict__ proj_w, const float* __restrict__ proj_b,
                 float* __restrict__ out_vhw)
{
    int blk = blockIdx.x;             // 24 = 8 batches * 3 priors
    int b = blk / 3, p = blk % 3;
    int t = threadIdx.x;
    __shared__ float prr[96], vf[96];
    const float* src = (p == 0) ? uk : (p == 1) ? fg : bg;
    if (t < 96) prr[t] = src[b * 96 + t];
    __syncthreads();
    if (t < 96) {
        float acc = qkv_b[192 + t];
        for (int k = 0; k < 96; ++k)
            acc += prr[k] * qkv_w[(192 + t) * 96 + k];
        vf[t] = acc;
    }
    __syncthreads();
    if (t < 96) {
        float acc = proj_b[t];
        for (int c = 0; c < 96; ++c)
            acc += vf[c] * proj_w[t * 96 + c];
        out_vhw[(b * 3 + p) * 96 + t] = acc;
    }
}

extern "C" void kernel_launch(void* const* d_in, const int* in_sizes, int n_in,
                              void* d_out, int out_size, void* d_ws, size_t ws_size,
                              hipStream_t stream) {
    const float* x          = (const float*)d_in[0];
    const float* mask       = (const float*)d_in[1];
    const float* uk         = (const float*)d_in[2];
    const float* fg         = (const float*)d_in[3];
    const float* bg         = (const float*)d_in[4];
    const float* qkv_w      = (const float*)d_in[5];
    const float* qkv_b      = (const float*)d_in[6];
    const float* proj_w     = (const float*)d_in[7];
    const float* proj_b     = (const float*)d_in[8];
    const float* bias_table = (const float*)d_in[9];
    float* out = (float*)d_out;
    bf16* ws   = (bf16*)d_ws;

    pawsa_prep<<<144, 256, 0, stream>>>(qkv_w, proj_w, ws);
    pawsa_prior<<<24, 128, 0, stream>>>(uk, fg, bg, qkv_w, qkv_b, proj_w, proj_b,
                                        out + (size_t)8192 * 49 * 96);
    pawsa_main<<<8192, 512, 0, stream>>>(x, mask, uk, fg, bg,
                                         ws, qkv_b, ws + 27648, proj_b,
                                         bias_table, out);
}

// Round 13
// 238.073 us; speedup vs baseline: 2.0220x; 2.0220x over previous
//
#include <hip/hip_runtime.h>
#include <hip/hip_bf16.h>

// ---------------------------------------------------------------------------
// PAWSA fused windowed attention, MI355X / gfx950 — round 13.
// Inputs f32, output f32 (out0 [8192,49,96], out1 v_hw [8,3,96] at elem
// offset 38,535,168). One block per window (8192 x 256), bf16 MFMA 16x16x32.
// = R11 skeleton (377us, 4 blocks/CU, VGPR 64) + VALU diet:
//   - f2s via hardware (__bf16) cast (compiler fuses v_cvt_pk_bf16_f32),
//     replacing the ~5-op software __float2bfloat16 path (~160 cvts/wave).
//   - qkv_w / proj_w pre-converted to bf16 in d_ws (prep kernel) ->
//     weight fragments are single 16B loads, no f32->bf16 chains.
//   - VT writes packed as s16x4 (R12's conflict win).
// LDS 40,952 B -> 4 blocks/CU. R8/R9/R12 lesson: FETCH balloon == spill;
// keep live set ~<80 VGPRs, never force bounds below it.
// ---------------------------------------------------------------------------

typedef __bf16 bf16x8 __attribute__((ext_vector_type(8)));
typedef float  f32x4  __attribute__((ext_vector_type(4)));
typedef short  s16x4  __attribute__((ext_vector_type(4)));
using bf16 = __hip_bfloat16;

#define SCALE 0.17677669529663687f   // 32^-0.5

// LDS partition (units: 16-bit elements) — 20,476 shorts = 40,952 B
#define LDS_XQ    0       // [49][100] x_ext rows<49 -> q -> O
#define LDS_K     4900    // [52][100] k
#define LDS_P     10100   // [49][68]  P (bf16 probs, per head)
#define LDS_VT    13432   // [96][68]  v transposed: vt[h*32+d][token]
#define LDS_BIAS  19960   // [516]     bias_table (bf16)
#define LDS_TOT   20476

static __device__ inline float s2f(short s) {
    unsigned int u = ((unsigned int)(unsigned short)s) << 16;
    float f;
    __builtin_memcpy(&f, &u, 4);
    return f;
}
// HARDWARE bf16 convert (compiler emits v_cvt_pk_bf16_f32), not the
// software __float2bfloat16 RNE path (~5 VALU ops).
static __device__ inline short f2s(float f) {
    __bf16 h = (__bf16)f;
    short s;
    __builtin_memcpy(&s, &h, 2);
    return s;
}
static __device__ inline bf16x8 ldw8(const float* p) {   // f32 -> bf16 fragment
    f32x4 a = *reinterpret_cast<const f32x4*>(p);
    f32x4 b = *reinterpret_cast<const f32x4*>(p + 4);
    bf16x8 r;
    #pragma unroll
    for (int i = 0; i < 4; ++i) {
        r[i]     = (__bf16)a[i];
        r[i + 4] = (__bf16)b[i];
    }
    return r;
}

// ---- prep: convert qkv_w (27648) + proj_w (9216) to bf16 in d_ws ----
__global__ __launch_bounds__(256)
void pawsa_prep(const float* __restrict__ qkv_w, const float* __restrict__ proj_w,
                bf16* __restrict__ ws)
{
    int i = blockIdx.x * 256 + threadIdx.x;
    if (i < 27648)      ws[i] = __float2bfloat16(qkv_w[i]);
    else if (i < 36864) ws[i] = __float2bfloat16(proj_w[i - 27648]);
}

__global__ __launch_bounds__(256, 4)
void pawsa_main(const float* __restrict__ x, const float* __restrict__ mask,
                const float* __restrict__ uk, const float* __restrict__ fg,
                const float* __restrict__ bg,
                const bf16* __restrict__ wq,    // bf16 qkv_w (d_ws)
                const float* __restrict__ qkv_b,
                const bf16* __restrict__ wp,    // bf16 proj_w (d_ws)
                const float* __restrict__ proj_b,
                const float* __restrict__ bias_table, float* __restrict__ out)
{
    __shared__ short smem[LDS_TOT];

    const int tid  = threadIdx.x;
    const int w    = blockIdx.x;       // window id
    const int b    = w >> 10;          // batch (nW = 1024)
    const int wi   = w & 1023;         // window-in-batch
    const int lane = tid & 63;
    const int wid  = tid >> 6;         // wave id 0..3
    const int lr   = lane & 15;        // row/col within 16-tile
    const int lg   = lane >> 4;        // k-group 0..3

    // ---- X tile -> registers directly (rows<49 x, 49-51 priors, >=52 zero) --
    bf16x8 af[3][4];
    #pragma unroll
    for (int mt = 0; mt < 4; ++mt) {
        int n = mt * 16 + lr;
        #pragma unroll
        for (int ks = 0; ks < 3; ++ks) {
            bf16x8 a = (bf16x8)0;
            if (n < 49) {
                a = ldw8(x + ((size_t)w * 49 + n) * 96 + ks * 32 + lg * 8);
            } else if (n < 52) {
                const float* pr = (n == 49) ? uk : (n == 50) ? fg : bg;
                a = ldw8(pr + b * 96 + ks * 32 + lg * 8);
            }
            af[ks][mt] = a;
        }
    }

    // ---- bias_table -> LDS (covered by the post-scatter barrier) ----
    for (int i = tid; i < 516; i += 256) smem[LDS_BIAS + i] = f2s(bias_table[i]);

    // ---- QKV GEMM: wave-split tiles (0-4,5-9,10-14,13-17; 13,14 dup benign),
    //      bf16 weights = single 16B loads, immediate scatter ----
    const int nt0 = (wid < 3) ? wid * 5 : 13;
    #pragma unroll
    for (int i = 0; i < 5; ++i) {
        int o = (nt0 + i) * 16 + lr;          // output channel 0..287
        bf16x8 bw0 = *reinterpret_cast<const bf16x8*>(wq + o * 96 +  0 + lg * 8);
        bf16x8 bw1 = *reinterpret_cast<const bf16x8*>(wq + o * 96 + 32 + lg * 8);
        bf16x8 bw2 = *reinterpret_cast<const bf16x8*>(wq + o * 96 + 64 + lg * 8);
        float  qb  = qkv_b[o];
        f32x4 acc[4] = {(f32x4)0.f, (f32x4)0.f, (f32x4)0.f, (f32x4)0.f};
        #pragma unroll
        for (int mt = 0; mt < 4; ++mt) {
            acc[mt] = __builtin_amdgcn_mfma_f32_16x16x32_bf16(af[0][mt], bw0, acc[mt], 0, 0, 0);
            acc[mt] = __builtin_amdgcn_mfma_f32_16x16x32_bf16(af[1][mt], bw1, acc[mt], 0, 0, 0);
            acc[mt] = __builtin_amdgcn_mfma_f32_16x16x32_bf16(af[2][mt], bw2, acc[mt], 0, 0, 0);
        }
        int s = o / 96;                       // 0=q 1=k 2=v
        int rem = o - s * 96;
        #pragma unroll
        for (int mt = 0; mt < 4; ++mt) {
            if (s == 2) {                     // v: 4 consecutive tokens -> b64
                s16x4 pk;
                #pragma unroll
                for (int j = 0; j < 4; ++j) pk[j] = f2s(acc[mt][j] + qb);
                *reinterpret_cast<s16x4*>(
                    &smem[LDS_VT + rem * 68 + mt * 16 + lg * 4]) = pk;
            } else {
                #pragma unroll
                for (int j = 0; j < 4; ++j) {
                    int n = mt * 16 + lg * 4 + j;
                    short hv = f2s(acc[mt][j] + qb);
                    if (s == 0) { if (n < 49) smem[LDS_XQ + n * 100 + rem] = hv; }
                    else        { if (n < 52) smem[LDS_K  + n * 100 + rem] = hv; }
                }
            }
        }
    }

    // ---- mask loads (af dead; issued before barrier, consumed in heads) ----
    float mk[4][4];
    #pragma unroll
    for (int nt = 0; nt < 4; ++nt) {
        int c = nt * 16 + lr;
        #pragma unroll
        for (int j = 0; j < 4; ++j) {
            int n = wid * 16 + lg * 4 + j;
            float m = 0.f;
            if (c < 49 && n < 49)
                m = mask[(size_t)wi * 2401 + n * 49 + c];
            mk[nt][j] = m;
        }
    }

    __syncthreads();
    // From here: K, VT read-only; XQ/P rows wave-private.

    // REL_IDX packed (4 x u8 per int)
    int bidxp[4];
    #pragma unroll
    for (int nt = 0; nt < 4; ++nt) {
        int c = nt * 16 + lr;
        int p = 0;
        #pragma unroll
        for (int j = 0; j < 4; ++j) {
            int n = wid * 16 + lg * 4 + j;
            int idx = 171;
            if (c < 49) {
                idx = (n / 7 - c / 7 + 6) * 13 + ((n % 7) - (c % 7) + 6);
                if (idx > 171) idx = 171;     // garbage rows n>=49 (discarded)
            } else if (c < 52) {
                idx = 169 + (c - 49);
            }
            p |= idx << (8 * j);
        }
        bidxp[nt] = p;
    }

    // ---- per-head attention (wave-private rows; no barriers) ----
    #pragma unroll
    for (int h = 0; h < 3; ++h) {
        bf16x8 aq = *reinterpret_cast<const bf16x8*>(
            &smem[LDS_XQ + (wid * 16 + lr) * 100 + h * 32 + lg * 8]);
        f32x4 sacc[4];
        #pragma unroll
        for (int nt = 0; nt < 4; ++nt) {
            bf16x8 bk = *reinterpret_cast<const bf16x8*>(
                &smem[LDS_K + (nt * 16 + lr) * 100 + h * 32 + lg * 8]);
            sacc[nt] = __builtin_amdgcn_mfma_f32_16x16x32_bf16(aq, bk, (f32x4)0.f, 0, 0, 0);
        }
        float lgt[4][4];
        #pragma unroll
        for (int nt = 0; nt < 4; ++nt) {
            int c = nt * 16 + lr;
            #pragma unroll
            for (int j = 0; j < 4; ++j) {
                float v = -1e30f;
                if (c < 52) {
                    int idx = (bidxp[nt] >> (8 * j)) & 255;
                    v = sacc[nt][j] * SCALE
                        + s2f(smem[LDS_BIAS + idx * 3 + h]) + mk[nt][j];
                }
                lgt[nt][j] = v;
            }
        }
        float pr[4][4];
        #pragma unroll
        for (int j = 0; j < 4; ++j) {
            float m = fmaxf(fmaxf(lgt[0][j], lgt[1][j]), fmaxf(lgt[2][j], lgt[3][j]));
            m = fmaxf(m, __shfl_xor(m, 1));
            m = fmaxf(m, __shfl_xor(m, 2));
            m = fmaxf(m, __shfl_xor(m, 4));
            m = fmaxf(m, __shfl_xor(m, 8));
            float sum = 0.f;
            #pragma unroll
            for (int nt = 0; nt < 4; ++nt) {
                pr[nt][j] = __expf(lgt[nt][j] - m);
                sum += pr[nt][j];
            }
            sum += __shfl_xor(sum, 1);
            sum += __shfl_xor(sum, 2);
            sum += __shfl_xor(sum, 4);
            sum += __shfl_xor(sum, 8);
            float inv = 1.0f / sum;
            #pragma unroll
            for (int nt = 0; nt < 4; ++nt) pr[nt][j] *= inv;
        }
        #pragma unroll
        for (int nt = 0; nt < 4; ++nt)
            #pragma unroll
            for (int j = 0; j < 4; ++j) {
                int prow = wid * 16 + lg * 4 + j;
                if (prow < 49)
                    smem[LDS_P + prow * 68 + nt * 16 + lr] = f2s(pr[nt][j]);
            }

        // O_h = P @ V (K=52 padded to 64; P cols 52-63 exact zeros)
        f32x4 ov[2] = {(f32x4)0.f, (f32x4)0.f};
        #pragma unroll
        for (int ks = 0; ks < 2; ++ks) {
            bf16x8 ap = *reinterpret_cast<const bf16x8*>(
                &smem[LDS_P + (wid * 16 + lr) * 68 + ks * 32 + lg * 8]);
            #pragma unroll
            for (int nt2 = 0; nt2 < 2; ++nt2) {
                bf16x8 bv = *reinterpret_cast<const bf16x8*>(
                    &smem[LDS_VT + (h * 32 + nt2 * 16 + lr) * 68 + ks * 32 + lg * 8]);
                ov[nt2] = __builtin_amdgcn_mfma_f32_16x16x32_bf16(ap, bv, ov[nt2], 0, 0, 0);
            }
        }
        #pragma unroll
        for (int nt2 = 0; nt2 < 2; ++nt2)
            #pragma unroll
            for (int j = 0; j < 4; ++j) {
                int orow = wid * 16 + lg * 4 + j;
                if (orow < 49)
                    smem[LDS_XQ + orow * 100 + h * 32 + nt2 * 16 + lr]
                        = f2s(ov[nt2][j]);
            }
    }

    // ---- projection: [64x96] @ proj_w^T[96x96] (wave-private rows) ----
    f32x4 po[6];
    #pragma unroll
    for (int nt = 0; nt < 6; ++nt) po[nt] = (f32x4)0.f;
    #pragma unroll
    for (int ks = 0; ks < 3; ++ks) {
        bf16x8 a = *reinterpret_cast<const bf16x8*>(
            &smem[LDS_XQ + (wid * 16 + lr) * 100 + ks * 32 + lg * 8]);
        #pragma unroll
        for (int nt = 0; nt < 6; ++nt) {
            bf16x8 bp = *reinterpret_cast<const bf16x8*>(
                wp + (nt * 16 + lr) * 96 + ks * 32 + lg * 8);
            po[nt] = __builtin_amdgcn_mfma_f32_16x16x32_bf16(a, bp, po[nt], 0, 0, 0);
        }
    }
    #pragma unroll
    for (int nt = 0; nt < 6; ++nt) {
        float pb = proj_b[nt * 16 + lr];
        #pragma unroll
        for (int j = 0; j < 4; ++j) {
            int n = wid * 16 + lg * 4 + j;
            if (n < 49)
                out[((size_t)w * 49 + n) * 96 + nt * 16 + lr] = po[nt][j] + pb;
        }
    }
}

// ---------------- prior highway: v_hw = proj(v(qkv(prior))) ----------------
__global__ __launch_bounds__(128)
void pawsa_prior(const float* __restrict__ uk, const float* __restrict__ fg,
                 const float* __restrict__ bg,
                 const float* __restrict__ qkv_w, const float* __restrict__ qkv_b,
                 const float* __restrict__ proj_w, const float* __restrict__ proj_b,
                 float* __restrict__ out_vhw)
{
    int blk = blockIdx.x;             // 24 = 8 batches * 3 priors
    int b = blk / 3, p = blk % 3;
    int t = threadIdx.x;
    __shared__ float prr[96], vf[96];
    const float* src = (p == 0) ? uk : (p == 1) ? fg : bg;
    if (t < 96) prr[t] = src[b * 96 + t];
    __syncthreads();
    if (t < 96) {
        float acc = qkv_b[192 + t];
        for (int k = 0; k < 96; ++k)
            acc += prr[k] * qkv_w[(192 + t) * 96 + k];
        vf[t] = acc;
    }
    __syncthreads();
    if (t < 96) {
        float acc = proj_b[t];
        for (int c = 0; c < 96; ++c)
            acc += vf[c] * proj_w[t * 96 + c];
        out_vhw[(b * 3 + p) * 96 + t] = acc;
    }
}

extern "C" void kernel_launch(void* const* d_in, const int* in_sizes, int n_in,
                              void* d_out, int out_size, void* d_ws, size_t ws_size,
                              hipStream_t stream) {
    const float* x          = (const float*)d_in[0];
    const float* mask       = (const float*)d_in[1];
    const float* uk         = (const float*)d_in[2];
    const float* fg         = (const float*)d_in[3];
    const float* bg         = (const float*)d_in[4];
    const float* qkv_w      = (const float*)d_in[5];
    const float* qkv_b      = (const float*)d_in[6];
    const float* proj_w     = (const float*)d_in[7];
    const float* proj_b     = (const float*)d_in[8];
    const float* bias_table = (const float*)d_in[9];
    float* out = (float*)d_out;
    bf16* ws   = (bf16*)d_ws;

    pawsa_prep<<<144, 256, 0, stream>>>(qkv_w, proj_w, ws);
    pawsa_prior<<<24, 128, 0, stream>>>(uk, fg, bg, qkv_w, qkv_b, proj_w, proj_b,
                                        out + (size_t)8192 * 49 * 96);
    pawsa_main<<<8192, 256, 0, stream>>>(x, mask, uk, fg, bg,
                                         ws, qkv_b, ws + 27648, proj_b,
                                         bias_table, out);
}